// Round 2
// baseline (17288.974 us; speedup 1.0000x reference)
//
// FineTuneMolFormer — Round 1: fp32 baseline, workspace shrunk to ~203 MB.
// R0 aborted with a GPU memory fault; theory = d_ws smaller than the 505 MB
// we used. New plan: 2 TD-sized slots in d_ws (X residual + bufA), and d_out
// (exactly TD floats) doubles as bufB (PHQ/PHK maps + residual-sum outputs).
// Q/K paths serialized so bufA is reused: Q->phiQ, K->phiK, V, attn-out, FFN.
#include <hip/hip_runtime.h>
#include <math.h>

#define Bsz 16
#define Lseq 2048
#define Dm 768
#define Hn 12
#define HDim 64
#define Fdim 32
#define NLayers 4
#define NTOK (Bsz * Lseq)

// ---------------------------------------------------------------------------
// SGEMM: C[M=NTOK][N=768] = A[M][K=768] @ W[K][N] + bias (+res) (opt gelu)
// 64x64 block tile, BK=16, 256 threads, 4x4 per-thread micro-tile.
// ---------------------------------------------------------------------------
__global__ __launch_bounds__(256) void sgemm_bias_kernel(
    const float* __restrict__ A, const float* __restrict__ W,
    const float* __restrict__ bias, const float* __restrict__ res,
    float* __restrict__ C, int act) {
  const int N = Dm, K = Dm;
  __shared__ float As[16][65];  // As[k][m], +1 pad breaks store conflicts
  __shared__ float Bs[16][68];  // Bs[k][n], +4 pad keeps float4 alignment
  int tid = threadIdx.x;
  int tx = tid & 15, ty = tid >> 4;
  int row0 = blockIdx.y * 64;
  int col0 = blockIdx.x * 64;
  int a_r = tid >> 2, a_c = (tid & 3) << 2;   // A loader: 64 rows x 16 k
  int b_r = tid >> 4, b_c = (tid & 15) << 2;  // W loader: 16 k x 64 n
  float acc[4][4] = {};
  for (int k0 = 0; k0 < K; k0 += 16) {
    float4 av = *(const float4*)(A + (size_t)(row0 + a_r) * K + (k0 + a_c));
    As[a_c + 0][a_r] = av.x;
    As[a_c + 1][a_r] = av.y;
    As[a_c + 2][a_r] = av.z;
    As[a_c + 3][a_r] = av.w;
    float4 wv = *(const float4*)(W + (size_t)(k0 + b_r) * N + (col0 + b_c));
    *(float4*)(&Bs[b_r][b_c]) = wv;
    __syncthreads();
#pragma unroll
    for (int kk = 0; kk < 16; ++kk) {
      float a_reg[4], b_reg[4];
#pragma unroll
      for (int i = 0; i < 4; ++i) a_reg[i] = As[kk][(ty << 2) + i];
#pragma unroll
      for (int j = 0; j < 4; ++j) b_reg[j] = Bs[kk][(tx << 2) + j];
#pragma unroll
      for (int i = 0; i < 4; ++i)
#pragma unroll
        for (int j = 0; j < 4; ++j)
          acc[i][j] = fmaf(a_reg[i], b_reg[j], acc[i][j]);
    }
    __syncthreads();
  }
#pragma unroll
  for (int i = 0; i < 4; ++i) {
    int r = row0 + (ty << 2) + i;
#pragma unroll
    for (int j = 0; j < 4; ++j) {
      int c = col0 + (tx << 2) + j;
      float v = acc[i][j] + bias[c];
      if (res) v += res[(size_t)r * N + c];
      if (act) v = 0.5f * v * (1.0f + erff(v * 0.70710678118654752f));
      C[(size_t)r * N + c] = v;
    }
  }
}

// ---------------------------------------------------------------------------
// Embedding gather: X[t,d] = tok_emb[idx[t], d]
// ---------------------------------------------------------------------------
__global__ __launch_bounds__(256) void embed_kernel(
    const int* __restrict__ idx, const float* __restrict__ emb,
    float* __restrict__ X) {
  int o = blockIdx.x * 256 + threadIdx.x;  // < NTOK*Dm
  int t = o / Dm, d = o - t * Dm;
  X[o] = emb[(size_t)idx[t] * Dm + d];
}

// ---------------------------------------------------------------------------
// Rotary in-place on (B,L,H,HD). thread = (t,h,j), j in [0,32): pair (j,j+32)
// ---------------------------------------------------------------------------
__global__ __launch_bounds__(256) void rotary_kernel(float* __restrict__ q) {
  int o = blockIdx.x * 256 + threadIdx.x;  // < NTOK*Hn*32
  int j = o & 31;
  int h = (o >> 5) % Hn;
  int t = o / (Hn * 32);
  int l = t & (Lseq - 1);
  size_t base = (size_t)t * Dm + h * HDim;
  float inv = expf(-(float)j * (9.210340371976184f / 32.0f));
  float fr = (float)l * inv;
  float s, c;
  sincosf(fr, &s, &c);
  float x1 = q[base + j], x2 = q[base + j + 32];
  q[base + j] = x1 * c - x2 * s;
  q[base + j + 32] = x2 * c + x1 * s;
}

// ---------------------------------------------------------------------------
// phi = relu(q @ omega) [* mask]  : (B,L,H,HD) x (HD,F) -> (B,L,H,F)
// ---------------------------------------------------------------------------
__global__ __launch_bounds__(256) void phi_kernel(
    const float* __restrict__ qk, const float* __restrict__ omega,
    const int* __restrict__ mask, float* __restrict__ ph) {
  __shared__ float om[HDim * Fdim];
  int tid = threadIdx.x;
  for (int i = tid; i < HDim * Fdim; i += 256) om[i] = omega[i];
  __syncthreads();
  int o = blockIdx.x * 256 + tid;  // < NTOK*Hn*Fdim
  int f = o & 31;
  int h = (o >> 5) % Hn;
  int t = o / (Hn * Fdim);
  const float* qr = qk + (size_t)t * Dm + h * HDim;
  float acc = 0.0f;
#pragma unroll
  for (int d = 0; d < HDim; ++d) acc = fmaf(qr[d], om[d * Fdim + f], acc);
  acc = fmaxf(acc, 0.0f);
  if (mask) acc *= (float)mask[t];
  ph[o] = acc;
}

// ---------------------------------------------------------------------------
// kv[b,h,f,d] = sum_l phk[b,l,h,f]*v[b,l,h,d];  ksum[b,h,f] = sum_l phk
// one block per (b,h); thread owns one f and 8 consecutive d.
// ---------------------------------------------------------------------------
__global__ __launch_bounds__(256) void kvsum_kernel(
    const float* __restrict__ phk, const float* __restrict__ v,
    float* __restrict__ kv, float* __restrict__ ksum) {
  __shared__ float ph_s[16][Fdim];
  __shared__ float v_s[16][HDim];
  int bh = blockIdx.x;  // b*Hn + h
  int b = bh / Hn, h = bh - b * Hn;
  int tid = threadIdx.x;
  int f = tid >> 3, d0 = (tid & 7) << 3;
  float acc[8] = {};
  float ks = 0.0f;
  for (int l0 = 0; l0 < Lseq; l0 += 16) {
    for (int i = tid; i < 16 * Fdim; i += 256) {
      int l = i >> 5, ff = i & 31;
      ph_s[l][ff] = phk[((size_t)(b * Lseq + l0 + l) * Hn + h) * Fdim + ff];
    }
    for (int i = tid; i < 16 * HDim; i += 256) {
      int l = i >> 6, dd = i & 63;
      v_s[l][dd] = v[((size_t)(b * Lseq + l0 + l) * Hn + h) * HDim + dd];
    }
    __syncthreads();
#pragma unroll
    for (int l = 0; l < 16; ++l) {
      float p = ph_s[l][f];
      ks += p;
#pragma unroll
      for (int q = 0; q < 8; ++q) acc[q] = fmaf(p, v_s[l][d0 + q], acc[q]);
    }
    __syncthreads();
  }
  size_t base = ((size_t)bh * Fdim + f) * HDim + d0;
  for (int q = 0; q < 8; ++q) kv[base + q] = acc[q];
  if ((tid & 7) == 0) ksum[bh * Fdim + f] = ks;  // 8 threads computed same ks
}

// ---------------------------------------------------------------------------
// out[t,h,d] = (sum_f phq*kv[b,h,f,d]) / (sum_f phq*ksum[b,h,f] + 1e-6)
// ---------------------------------------------------------------------------
__global__ __launch_bounds__(256) void attn_out_kernel(
    const float* __restrict__ phq, const float* __restrict__ kv,
    const float* __restrict__ ksum, float* __restrict__ out) {
  int o = blockIdx.x * 256 + threadIdx.x;  // < NTOK*Dm
  int d = o & 63;
  int h = (o >> 6) % Hn;
  int t = o / Dm;
  int b = t >> 11;  // t / Lseq
  const float* pq = phq + (size_t)t * (Hn * Fdim) + h * Fdim;
  const float* ks = ksum + ((size_t)b * Hn + h) * Fdim;
  const float* kvp = kv + ((size_t)(b * Hn + h) * Fdim) * HDim + d;
  float zden = 0.0f, acc = 0.0f;
#pragma unroll
  for (int f = 0; f < Fdim; ++f) {
    float p = pq[f];
    zden = fmaf(p, ks[f], zden);
    acc = fmaf(p, kvp[(size_t)f * HDim], acc);
  }
  out[o] = acc / (zden + 1e-6f);
}

// ---------------------------------------------------------------------------
// LayerNorm over last dim (768): one block per token, 3 elems per thread.
// ---------------------------------------------------------------------------
__global__ __launch_bounds__(256) void layernorm_kernel(
    const float* __restrict__ x, const float* __restrict__ g,
    const float* __restrict__ be, float* __restrict__ out) {
  __shared__ float red[256];
  int t = blockIdx.x, tid = threadIdx.x;
  const float* xr = x + (size_t)t * Dm;
  float v0 = xr[tid], v1 = xr[tid + 256], v2 = xr[tid + 512];
  red[tid] = v0 + v1 + v2;
  __syncthreads();
  for (int off = 128; off > 0; off >>= 1) {
    if (tid < off) red[tid] += red[tid + off];
    __syncthreads();
  }
  float mu = red[0] * (1.0f / 768.0f);
  __syncthreads();
  float d0 = v0 - mu, d1 = v1 - mu, d2 = v2 - mu;
  red[tid] = d0 * d0 + d1 * d1 + d2 * d2;
  __syncthreads();
  for (int off = 128; off > 0; off >>= 1) {
    if (tid < off) red[tid] += red[tid + off];
    __syncthreads();
  }
  float rs = rsqrtf(red[0] * (1.0f / 768.0f) + 1e-5f);
  float* outr = out + (size_t)t * Dm;
  outr[tid] = d0 * rs * g[tid] + be[tid];
  outr[tid + 256] = d1 * rs * g[tid + 256] + be[tid + 256];
  outr[tid + 512] = d2 * rs * g[tid + 512] + be[tid + 512];
}

// ---------------------------------------------------------------------------
extern "C" void kernel_launch(void* const* d_in, const int* in_sizes, int n_in,
                              void* d_out, int out_size, void* d_ws,
                              size_t ws_size, hipStream_t stream) {
  const int* idx = (const int*)d_in[0];
  const int* mask = (const int*)d_in[1];
  const float* tok_emb = (const float*)d_in[2];
  const float* Wq = (const float*)d_in[3];
  const float* bq = (const float*)d_in[4];
  const float* Wk = (const float*)d_in[5];
  const float* bk = (const float*)d_in[6];
  const float* Wv = (const float*)d_in[7];
  const float* bv = (const float*)d_in[8];
  const float* Wo = (const float*)d_in[9];
  const float* bo = (const float*)d_in[10];
  const float* omega = (const float*)d_in[11];
  const float* W1 = (const float*)d_in[12];
  const float* b1 = (const float*)d_in[13];
  const float* W2 = (const float*)d_in[14];
  const float* b2 = (const float*)d_in[15];
  const float* g1 = (const float*)d_in[16];
  const float* be1 = (const float*)d_in[17];
  const float* g2 = (const float*)d_in[18];
  const float* be2 = (const float*)d_in[19];
  const float* gf = (const float*)d_in[20];
  const float* bf = (const float*)d_in[21];

  float* ws = (float*)d_ws;
  const size_t TD = (size_t)NTOK * Dm;
  // Workspace plan (~203 MB in d_ws; d_out doubles as bufB):
  //  X    (ws)    : residual / layer input            [TD]
  //  bufA (ws+TD) : Q -> K -> V -> attn-out -> FFN-hidden [TD]
  //  KV,KSUM      : per-(b,h) linear-attention state   [~0.4M floats]
  //  bufB = d_out : PHQ (lower half) + PHK (upper half) -> x+attn -> x+ffn
  float* X = ws;
  float* bufA = ws + TD;
  float* KV = ws + 2 * TD;
  float* KSUM = KV + (size_t)Bsz * Hn * Fdim * HDim;
  float* bufB = (float*)d_out;  // TD floats exactly (out_size == NTOK*Dm)
  float* PHQ = bufB;                               // NTOK*Hn*Fdim = TD/2
  float* PHK = bufB + (size_t)NTOK * Hn * Fdim;    // TD/2

  dim3 gg(Dm / 64, NTOK / 64), gb(256);
  const int rot_grid = (NTOK * Hn * 32) / 256;
  const int phi_grid = (NTOK * Hn * Fdim) / 256;
  const int elem_grid = (NTOK * Dm) / 256;

  embed_kernel<<<elem_grid, 256, 0, stream>>>(idx, tok_emb, X);

  for (int i = 0; i < NLayers; ++i) {
    const float* wq = Wq + (size_t)i * Dm * Dm;
    const float* wk = Wk + (size_t)i * Dm * Dm;
    const float* wv = Wv + (size_t)i * Dm * Dm;
    const float* wo = Wo + (size_t)i * Dm * Dm;
    const float* w1 = W1 + (size_t)i * Dm * Dm;
    const float* w2 = W2 + (size_t)i * Dm * Dm;
    const float* omi = omega + (size_t)i * HDim * Fdim;

    // Q path -> PHQ (bufA reused afterwards)
    sgemm_bias_kernel<<<gg, gb, 0, stream>>>(X, wq, bq + (size_t)i * Dm,
                                             nullptr, bufA, 0);
    rotary_kernel<<<rot_grid, 256, 0, stream>>>(bufA);
    phi_kernel<<<phi_grid, 256, 0, stream>>>(bufA, omi, nullptr, PHQ);
    // K path -> PHK
    sgemm_bias_kernel<<<gg, gb, 0, stream>>>(X, wk, bk + (size_t)i * Dm,
                                             nullptr, bufA, 0);
    rotary_kernel<<<rot_grid, 256, 0, stream>>>(bufA);
    phi_kernel<<<phi_grid, 256, 0, stream>>>(bufA, omi, mask, PHK);
    // V -> bufA
    sgemm_bias_kernel<<<gg, gb, 0, stream>>>(X, wv, bv + (size_t)i * Dm,
                                             nullptr, bufA, 0);
    kvsum_kernel<<<Bsz * Hn, 256, 0, stream>>>(PHK, bufA, KV, KSUM);
    // attn combine -> bufA (V dead after kvsum; stream-ordered)
    attn_out_kernel<<<elem_grid, 256, 0, stream>>>(PHQ, KV, KSUM, bufA);
    // x + attn@Wo + bo -> bufB (PHQ/PHK dead)
    sgemm_bias_kernel<<<gg, gb, 0, stream>>>(bufA, wo, bo + (size_t)i * Dm, X,
                                             bufB, 0);
    // LN1 -> X (post-LN value is both FFN input and FFN residual)
    layernorm_kernel<<<NTOK, 256, 0, stream>>>(bufB, g1 + (size_t)i * Dm,
                                               be1 + (size_t)i * Dm, X);
    // gelu(X@W1+b1) -> bufA
    sgemm_bias_kernel<<<gg, gb, 0, stream>>>(X, w1, b1 + (size_t)i * Dm,
                                             nullptr, bufA, 1);
    // X + bufA@W2+b2 -> bufB
    sgemm_bias_kernel<<<gg, gb, 0, stream>>>(bufA, w2, b2 + (size_t)i * Dm, X,
                                             bufB, 0);
    // LN2 -> X (next layer input)
    layernorm_kernel<<<NTOK, 256, 0, stream>>>(bufB, g2 + (size_t)i * Dm,
                                               be2 + (size_t)i * Dm, X);
  }
  // Final LN: reads X, writes d_out (bufB content dead).
  layernorm_kernel<<<NTOK, 256, 0, stream>>>(X, gf, bf, (float*)d_out);
}

// Round 3
// 5134.212 us; speedup vs baseline: 3.3674x; 3.3674x over previous
//
// FineTuneMolFormer — Round 2: bf16 MFMA GEMM (m97 recipe) replaces fp32 SGEMM.
// GEMMs were 88% of 17.3 ms at 66 TF on the fp32 VALU. Now: 128x128 tile,
// BK=32, 4 waves x 4x4 mfma_f32_16x16x32_bf16, global_load_lds width=16.
// Weights pre-transposed to bf16 N-major once per launch (both MFMA operands
// need K-contiguous). Activations bf16; accumulation fp32 everywhere.
// d_ws: 6 W^T (28 MB) + 3 TD bf16 bufs (151 MB) + KV state = ~181 MB.
// PHQ/PHK live in d_out (dead before final LN writes it).
#include <hip/hip_runtime.h>
#include <math.h>

#define Bsz 16
#define Lseq 2048
#define Dm 768
#define Hn 12
#define HDim 64
#define Fdim 32
#define NLayers 4
#define NTOK (Bsz * Lseq)

typedef __bf16 bf16;
typedef bf16 bf16x8 __attribute__((ext_vector_type(8)));
typedef float f32x4 __attribute__((ext_vector_type(4)));

#define AS1(p) ((__attribute__((address_space(1))) void*)(uintptr_t)(p))
#define AS3(p) ((__attribute__((address_space(3))) void*)(p))

// ---------------------------------------------------------------------------
// Weight convert+transpose: W[l][k][n] fp32 -> Wt[l][n][k] bf16. 32x32 tiles.
// ---------------------------------------------------------------------------
__global__ __launch_bounds__(256) void wconv_kernel(const float* __restrict__ W,
                                                    bf16* __restrict__ Wt) {
  __shared__ float t[32][33];
  int l = blockIdx.z;
  int kb = blockIdx.y * 32, nb = blockIdx.x * 32;
  const float* Wl = W + (size_t)l * Dm * Dm;
  bf16* Wtl = Wt + (size_t)l * Dm * Dm;
  int tx = threadIdx.x, ty = threadIdx.y;  // 32 x 8
#pragma unroll
  for (int i = 0; i < 32; i += 8)
    t[ty + i][tx] = Wl[(size_t)(kb + ty + i) * Dm + nb + tx];
  __syncthreads();
#pragma unroll
  for (int i = 0; i < 32; i += 8)
    Wtl[(size_t)(nb + ty + i) * Dm + kb + tx] = (bf16)t[tx][ty + i];
}

// ---------------------------------------------------------------------------
// bf16 MFMA GEMM: C[M][N=768] = A[M][K=768] @ Wt[N][K]^T + bias (+res)(+gelu)
// 128x128 tile, BK=32, 256 thr (4 waves), wave = 64x64 quadrant = 4x4 MFMAs.
// Staging via global_load_lds width=16 (chunk c = 16B: row c>>2, seg c&3).
// ---------------------------------------------------------------------------
__global__ __launch_bounds__(256) void gemm_mfma_kernel(
    const bf16* __restrict__ A, const bf16* __restrict__ Wt,
    const float* __restrict__ bias, const bf16* __restrict__ res,
    bf16* __restrict__ C, int act) {
  const int K = Dm, N = Dm;
  __shared__ bf16 As[128 * 32];
  __shared__ bf16 Bs[128 * 32];
  const int tid = threadIdx.x;
  const int lane = tid & 63;
  const int wave = tid >> 6;
  const int wr = (wave >> 1) << 6;  // wave row offset in 128-tile
  const int wc = (wave & 1) << 6;   // wave col offset
  const int m0 = blockIdx.y << 7;
  const int n0 = blockIdx.x << 7;
  const int c0 = tid, c1 = tid + 256;  // 16B chunks this thread stages
  const bf16* a0 = A + (size_t)(m0 + (c0 >> 2)) * K + ((c0 & 3) << 3);
  const bf16* a1 = A + (size_t)(m0 + (c1 >> 2)) * K + ((c1 & 3) << 3);
  const bf16* b0 = Wt + (size_t)(n0 + (c0 >> 2)) * K + ((c0 & 3) << 3);
  const bf16* b1 = Wt + (size_t)(n0 + (c1 >> 2)) * K + ((c1 & 3) << 3);
  bf16* const As0 = As + c0 * 8;
  bf16* const As1 = As + c1 * 8;
  bf16* const Bs0 = Bs + c0 * 8;
  bf16* const Bs1 = Bs + c1 * 8;

  const int la = lane & 15, qd = lane >> 4;
  const int aoff = (wr + la) * 32 + qd * 8;  // A frag base (elem), +i*512
  const int boff = (wc + la) * 32 + qd * 8;  // B frag base, +j*512

  f32x4 acc[4][4] = {};

  for (int k0 = 0; k0 < K; k0 += 32) {
    __builtin_amdgcn_global_load_lds(AS1(a0 + k0), AS3(As0), 16, 0, 0);
    __builtin_amdgcn_global_load_lds(AS1(a1 + k0), AS3(As1), 16, 0, 0);
    __builtin_amdgcn_global_load_lds(AS1(b0 + k0), AS3(Bs0), 16, 0, 0);
    __builtin_amdgcn_global_load_lds(AS1(b1 + k0), AS3(Bs1), 16, 0, 0);
    __syncthreads();
    bf16x8 af[4], bfr[4];
#pragma unroll
    for (int i = 0; i < 4; ++i)
      af[i] = *(const bf16x8*)(As + aoff + i * 512);
#pragma unroll
    for (int j = 0; j < 4; ++j)
      bfr[j] = *(const bf16x8*)(Bs + boff + j * 512);
#pragma unroll
    for (int i = 0; i < 4; ++i)
#pragma unroll
      for (int j = 0; j < 4; ++j)
        acc[i][j] = __builtin_amdgcn_mfma_f32_16x16x32_bf16(af[i], bfr[j],
                                                            acc[i][j], 0, 0, 0);
    __syncthreads();
  }

  // C/D layout: col = lane&15, row = (lane>>4)*4 + reg  [m89/m91-verified]
#pragma unroll
  for (int i = 0; i < 4; ++i) {
    int rbase = m0 + wr + i * 16 + qd * 4;
#pragma unroll
    for (int j = 0; j < 4; ++j) {
      int col = n0 + wc + j * 16 + la;
      float bc = bias[col];
#pragma unroll
      for (int r = 0; r < 4; ++r) {
        int row = rbase + r;
        float v = acc[i][j][r] + bc;
        if (res) v += (float)res[(size_t)row * N + col];
        if (act) v = 0.5f * v * (1.0f + erff(v * 0.70710678118654752f));
        C[(size_t)row * N + col] = (bf16)v;
      }
    }
  }
}

// ---------------------------------------------------------------------------
// Embedding gather -> bf16
// ---------------------------------------------------------------------------
__global__ __launch_bounds__(256) void embed_kernel(
    const int* __restrict__ idx, const float* __restrict__ emb,
    bf16* __restrict__ X) {
  int o = blockIdx.x * 256 + threadIdx.x;
  int t = o / Dm, d = o - t * Dm;
  X[o] = (bf16)emb[(size_t)idx[t] * Dm + d];
}

// ---------------------------------------------------------------------------
// Rotary in-place (bf16 storage, fp32 math)
// ---------------------------------------------------------------------------
__global__ __launch_bounds__(256) void rotary_kernel(bf16* __restrict__ q) {
  int o = blockIdx.x * 256 + threadIdx.x;  // < NTOK*Hn*32
  int j = o & 31;
  int h = (o >> 5) % Hn;
  int t = o / (Hn * 32);
  int l = t & (Lseq - 1);
  size_t base = (size_t)t * Dm + h * HDim;
  float inv = expf(-(float)j * (9.210340371976184f / 32.0f));
  float fr = (float)l * inv;
  float s, c;
  sincosf(fr, &s, &c);
  float x1 = (float)q[base + j], x2 = (float)q[base + j + 32];
  q[base + j] = (bf16)(x1 * c - x2 * s);
  q[base + j + 32] = (bf16)(x2 * c + x1 * s);
}

// ---------------------------------------------------------------------------
// phi = relu(q @ omega) [* mask] : bf16 in, bf16 out, fp32 accumulate
// ---------------------------------------------------------------------------
__global__ __launch_bounds__(256) void phi_kernel(
    const bf16* __restrict__ qk, const float* __restrict__ omega,
    const int* __restrict__ mask, bf16* __restrict__ ph) {
  __shared__ float om[HDim * Fdim];
  int tid = threadIdx.x;
  for (int i = tid; i < HDim * Fdim; i += 256) om[i] = omega[i];
  __syncthreads();
  int o = blockIdx.x * 256 + tid;  // < NTOK*Hn*Fdim
  int f = o & 31;
  int h = (o >> 5) % Hn;
  int t = o / (Hn * Fdim);
  const bf16* qr = qk + (size_t)t * Dm + h * HDim;
  float acc = 0.0f;
#pragma unroll
  for (int d = 0; d < HDim; ++d)
    acc = fmaf((float)qr[d], om[d * Fdim + f], acc);
  acc = fmaxf(acc, 0.0f);
  if (mask) acc *= (float)mask[t];
  ph[o] = (bf16)acc;
}

// ---------------------------------------------------------------------------
// kv[b,h,f,d] = sum_l phk*v ; ksum[b,h,f] = sum_l phk  (fp32 accumulate)
// ---------------------------------------------------------------------------
__global__ __launch_bounds__(256) void kvsum_kernel(
    const bf16* __restrict__ phk, const bf16* __restrict__ v,
    float* __restrict__ kv, float* __restrict__ ksum) {
  __shared__ float ph_s[16][Fdim];
  __shared__ float v_s[16][HDim];
  int bh = blockIdx.x;
  int b = bh / Hn, h = bh - b * Hn;
  int tid = threadIdx.x;
  int f = tid >> 3, d0 = (tid & 7) << 3;
  float acc[8] = {};
  float ks = 0.0f;
  for (int l0 = 0; l0 < Lseq; l0 += 16) {
    for (int i = tid; i < 16 * Fdim; i += 256) {
      int l = i >> 5, ff = i & 31;
      ph_s[l][ff] =
          (float)phk[((size_t)(b * Lseq + l0 + l) * Hn + h) * Fdim + ff];
    }
    for (int i = tid; i < 16 * HDim; i += 256) {
      int l = i >> 6, dd = i & 63;
      v_s[l][dd] = (float)v[((size_t)(b * Lseq + l0 + l) * Hn + h) * HDim + dd];
    }
    __syncthreads();
#pragma unroll
    for (int l = 0; l < 16; ++l) {
      float p = ph_s[l][f];
      ks += p;
#pragma unroll
      for (int q = 0; q < 8; ++q) acc[q] = fmaf(p, v_s[l][d0 + q], acc[q]);
    }
    __syncthreads();
  }
  size_t base = ((size_t)bh * Fdim + f) * HDim + d0;
  for (int q = 0; q < 8; ++q) kv[base + q] = acc[q];
  if ((tid & 7) == 0) ksum[bh * Fdim + f] = ks;
}

// ---------------------------------------------------------------------------
// out[t,h,d] = (sum_f phq*kv) / (sum_f phq*ksum + 1e-6) -> bf16
// ---------------------------------------------------------------------------
__global__ __launch_bounds__(256) void attn_out_kernel(
    const bf16* __restrict__ phq, const float* __restrict__ kv,
    const float* __restrict__ ksum, bf16* __restrict__ out) {
  int o = blockIdx.x * 256 + threadIdx.x;  // < NTOK*Dm
  int d = o & 63;
  int h = (o >> 6) % Hn;
  int t = o / Dm;
  int b = t >> 11;
  const bf16* pq = phq + (size_t)t * (Hn * Fdim) + h * Fdim;
  const float* ks = ksum + ((size_t)b * Hn + h) * Fdim;
  const float* kvp = kv + ((size_t)(b * Hn + h) * Fdim) * HDim + d;
  float zden = 0.0f, acc = 0.0f;
#pragma unroll
  for (int f = 0; f < Fdim; ++f) {
    float p = (float)pq[f];
    zden = fmaf(p, ks[f], zden);
    acc = fmaf(p, kvp[(size_t)f * HDim], acc);
  }
  out[o] = (bf16)(acc / (zden + 1e-6f));
}

// ---------------------------------------------------------------------------
// LayerNorm (bf16 in, OutT out), fp32 stats. One block per token.
// ---------------------------------------------------------------------------
template <typename OutT>
__global__ __launch_bounds__(256) void layernorm_kernel(
    const bf16* __restrict__ x, const float* __restrict__ g,
    const float* __restrict__ be, OutT* __restrict__ out) {
  __shared__ float red[256];
  int t = blockIdx.x, tid = threadIdx.x;
  const bf16* xr = x + (size_t)t * Dm;
  float v0 = (float)xr[tid], v1 = (float)xr[tid + 256],
        v2 = (float)xr[tid + 512];
  red[tid] = v0 + v1 + v2;
  __syncthreads();
  for (int off = 128; off > 0; off >>= 1) {
    if (tid < off) red[tid] += red[tid + off];
    __syncthreads();
  }
  float mu = red[0] * (1.0f / 768.0f);
  __syncthreads();
  float d0 = v0 - mu, d1 = v1 - mu, d2 = v2 - mu;
  red[tid] = d0 * d0 + d1 * d1 + d2 * d2;
  __syncthreads();
  for (int off = 128; off > 0; off >>= 1) {
    if (tid < off) red[tid] += red[tid + off];
    __syncthreads();
  }
  float rs = rsqrtf(red[0] * (1.0f / 768.0f) + 1e-5f);
  OutT* outr = out + (size_t)t * Dm;
  outr[tid] = (OutT)(d0 * rs * g[tid] + be[tid]);
  outr[tid + 256] = (OutT)(d1 * rs * g[tid + 256] + be[tid + 256]);
  outr[tid + 512] = (OutT)(d2 * rs * g[tid + 512] + be[tid + 512]);
}

// ---------------------------------------------------------------------------
extern "C" void kernel_launch(void* const* d_in, const int* in_sizes, int n_in,
                              void* d_out, int out_size, void* d_ws,
                              size_t ws_size, hipStream_t stream) {
  const int* idx = (const int*)d_in[0];
  const int* mask = (const int*)d_in[1];
  const float* tok_emb = (const float*)d_in[2];
  const float* Wq = (const float*)d_in[3];
  const float* bq = (const float*)d_in[4];
  const float* Wk = (const float*)d_in[5];
  const float* bk = (const float*)d_in[6];
  const float* Wv = (const float*)d_in[7];
  const float* bv = (const float*)d_in[8];
  const float* Wo = (const float*)d_in[9];
  const float* bo = (const float*)d_in[10];
  const float* omega = (const float*)d_in[11];
  const float* W1 = (const float*)d_in[12];
  const float* b1 = (const float*)d_in[13];
  const float* W2 = (const float*)d_in[14];
  const float* b2 = (const float*)d_in[15];
  const float* g1 = (const float*)d_in[16];
  const float* be1 = (const float*)d_in[17];
  const float* g2 = (const float*)d_in[18];
  const float* be2 = (const float*)d_in[19];
  const float* gf = (const float*)d_in[20];
  const float* bf = (const float*)d_in[21];

  const size_t TD = (size_t)NTOK * Dm;
  const size_t WSZ = (size_t)NLayers * Dm * Dm;  // bf16 elems per weight type
  bf16* wsb = (bf16*)d_ws;
  bf16* WqT = wsb;
  bf16* WkT = WqT + WSZ;
  bf16* WvT = WkT + WSZ;
  bf16* WoT = WvT + WSZ;
  bf16* W1T = WoT + WSZ;
  bf16* W2T = W1T + WSZ;
  bf16* Xb = wsb + 6 * WSZ;  // layer input / residual
  bf16* Ab = Xb + TD;        // q/k/v temp, h1, h2
  bf16* Bb = Ab + TD;        // attn-out, ffn hidden
  float* KV = (float*)(Bb + TD);
  float* KSUM = KV + (size_t)Bsz * Hn * Fdim * HDim;
  // d_ws usage ~181 MB (R1 proved >= 203 MB available)
  bf16* PHQ = (bf16*)d_out;  // dead before final LN writes d_out
  bf16* PHK = PHQ + (size_t)NTOK * Hn * Fdim;

  dim3 wg(Dm / 32, Dm / 32, NLayers), wb(32, 8);
  wconv_kernel<<<wg, wb, 0, stream>>>(Wq, WqT);
  wconv_kernel<<<wg, wb, 0, stream>>>(Wk, WkT);
  wconv_kernel<<<wg, wb, 0, stream>>>(Wv, WvT);
  wconv_kernel<<<wg, wb, 0, stream>>>(Wo, WoT);
  wconv_kernel<<<wg, wb, 0, stream>>>(W1, W1T);
  wconv_kernel<<<wg, wb, 0, stream>>>(W2, W2T);

  dim3 gg(Dm / 128, NTOK / 128), gb(256);
  const int rot_grid = (NTOK * Hn * 32) / 256;
  const int phi_grid = (NTOK * Hn * Fdim) / 256;
  const int elem_grid = (NTOK * Dm) / 256;

  embed_kernel<<<elem_grid, 256, 0, stream>>>(idx, tok_emb, Xb);

  for (int i = 0; i < NLayers; ++i) {
    const size_t wo = (size_t)i * Dm * Dm;
    const size_t bo_ = (size_t)i * Dm;
    const float* omi = omega + (size_t)i * HDim * Fdim;

    // Q -> Ab -> rotary -> PHQ
    gemm_mfma_kernel<<<gg, gb, 0, stream>>>(Xb, WqT + wo, bq + bo_, nullptr,
                                            Ab, 0);
    rotary_kernel<<<rot_grid, 256, 0, stream>>>(Ab);
    phi_kernel<<<phi_grid, 256, 0, stream>>>(Ab, omi, nullptr, PHQ);
    // K -> Ab -> rotary -> PHK (masked)
    gemm_mfma_kernel<<<gg, gb, 0, stream>>>(Xb, WkT + wo, bk + bo_, nullptr,
                                            Ab, 0);
    rotary_kernel<<<rot_grid, 256, 0, stream>>>(Ab);
    phi_kernel<<<phi_grid, 256, 0, stream>>>(Ab, omi, mask, PHK);
    // V -> Ab; kv state; attention combine -> Bb
    gemm_mfma_kernel<<<gg, gb, 0, stream>>>(Xb, WvT + wo, bv + bo_, nullptr,
                                            Ab, 0);
    kvsum_kernel<<<Bsz * Hn, 256, 0, stream>>>(PHK, Ab, KV, KSUM);
    attn_out_kernel<<<elem_grid, 256, 0, stream>>>(PHQ, KV, KSUM, Bb);
    // h1 = x + attn@Wo + bo -> Ab
    gemm_mfma_kernel<<<gg, gb, 0, stream>>>(Bb, WoT + wo, bo + bo_, Xb, Ab, 0);
    // LN1 -> Xb (FFN input AND FFN residual)
    layernorm_kernel<bf16><<<NTOK, 256, 0, stream>>>(Ab, g1 + bo_, be1 + bo_,
                                                     Xb);
    // gelu(Xb@W1+b1) -> Bb
    gemm_mfma_kernel<<<gg, gb, 0, stream>>>(Xb, W1T + wo, b1 + bo_, nullptr,
                                            Bb, 1);
    // h2 = Xb + Bb@W2+b2 -> Ab
    gemm_mfma_kernel<<<gg, gb, 0, stream>>>(Bb, W2T + wo, b2 + bo_, Xb, Ab, 0);
    // LN2 -> Xb (next layer input)
    layernorm_kernel<bf16><<<NTOK, 256, 0, stream>>>(Ab, g2 + bo_, be2 + bo_,
                                                     Xb);
  }
  layernorm_kernel<float><<<NTOK, 256, 0, stream>>>(Xb, gf, bf, (float*)d_out);
}

// Round 4
// 4493.953 us; speedup vs baseline: 3.8472x; 1.1425x over previous
//
// FineTuneMolFormer — Round 3: kvsum split-L (192→1536 blocks, atomics) +
// fp32 residual stream (Xf) with fused residual+LN. GEMM epilogue no longer
// does residual; LN reads raw bf16 y + fp32 Xf. Buffers:
//   ws  : 6 W^T bf16 (28.3) + Xf fp32 (100.7) + Ab bf16 (50.3) + KV (1.6) MB
//   d_out: [Xb bf16 50.3 MB][PHQ+PHK / y-buf bf16 50.3 MB]; final LN last.
#include <hip/hip_runtime.h>
#include <math.h>

#define Bsz 16
#define Lseq 2048
#define Dm 768
#define Hn 12
#define HDim 64
#define Fdim 32
#define NLayers 4
#define NTOK (Bsz * Lseq)
#define NSPLIT 8

typedef __bf16 bf16;
typedef bf16 bf16x8 __attribute__((ext_vector_type(8)));
typedef float f32x4 __attribute__((ext_vector_type(4)));

#define AS1(p) ((__attribute__((address_space(1))) void*)(uintptr_t)(p))
#define AS3(p) ((__attribute__((address_space(3))) void*)(p))

// ---------------------------------------------------------------------------
// Weight convert+transpose: W[l][k][n] fp32 -> Wt[l][n][k] bf16. 32x32 tiles.
// ---------------------------------------------------------------------------
__global__ __launch_bounds__(256) void wconv_kernel(const float* __restrict__ W,
                                                    bf16* __restrict__ Wt) {
  __shared__ float t[32][33];
  int l = blockIdx.z;
  int kb = blockIdx.y * 32, nb = blockIdx.x * 32;
  const float* Wl = W + (size_t)l * Dm * Dm;
  bf16* Wtl = Wt + (size_t)l * Dm * Dm;
  int tx = threadIdx.x, ty = threadIdx.y;  // 32 x 8
#pragma unroll
  for (int i = 0; i < 32; i += 8)
    t[ty + i][tx] = Wl[(size_t)(kb + ty + i) * Dm + nb + tx];
  __syncthreads();
#pragma unroll
  for (int i = 0; i < 32; i += 8)
    Wtl[(size_t)(nb + ty + i) * Dm + kb + tx] = (bf16)t[tx][ty + i];
}

// ---------------------------------------------------------------------------
// bf16 MFMA GEMM: C[M][N=768] = A[M][K=768] @ Wt[N][K]^T + bias (opt gelu)
// 128x128 tile, BK=32, 4 waves x 4x4 mfma_f32_16x16x32_bf16, width-16 LDS DMA.
// ---------------------------------------------------------------------------
__global__ __launch_bounds__(256) void gemm_mfma_kernel(
    const bf16* __restrict__ A, const bf16* __restrict__ Wt,
    const float* __restrict__ bias, bf16* __restrict__ C, int act) {
  const int K = Dm, N = Dm;
  __shared__ bf16 As[128 * 32];
  __shared__ bf16 Bs[128 * 32];
  const int tid = threadIdx.x;
  const int lane = tid & 63;
  const int wave = tid >> 6;
  const int wr = (wave >> 1) << 6;
  const int wc = (wave & 1) << 6;
  const int m0 = blockIdx.y << 7;
  const int n0 = blockIdx.x << 7;
  const int c0 = tid, c1 = tid + 256;
  const bf16* a0 = A + (size_t)(m0 + (c0 >> 2)) * K + ((c0 & 3) << 3);
  const bf16* a1 = A + (size_t)(m0 + (c1 >> 2)) * K + ((c1 & 3) << 3);
  const bf16* b0 = Wt + (size_t)(n0 + (c0 >> 2)) * K + ((c0 & 3) << 3);
  const bf16* b1 = Wt + (size_t)(n0 + (c1 >> 2)) * K + ((c1 & 3) << 3);
  bf16* const As0 = As + c0 * 8;
  bf16* const As1 = As + c1 * 8;
  bf16* const Bs0 = Bs + c0 * 8;
  bf16* const Bs1 = Bs + c1 * 8;

  const int la = lane & 15, qd = lane >> 4;
  const int aoff = (wr + la) * 32 + qd * 8;
  const int boff = (wc + la) * 32 + qd * 8;

  f32x4 acc[4][4] = {};

  for (int k0 = 0; k0 < K; k0 += 32) {
    __builtin_amdgcn_global_load_lds(AS1(a0 + k0), AS3(As0), 16, 0, 0);
    __builtin_amdgcn_global_load_lds(AS1(a1 + k0), AS3(As1), 16, 0, 0);
    __builtin_amdgcn_global_load_lds(AS1(b0 + k0), AS3(Bs0), 16, 0, 0);
    __builtin_amdgcn_global_load_lds(AS1(b1 + k0), AS3(Bs1), 16, 0, 0);
    __syncthreads();
    bf16x8 af[4], bfr[4];
#pragma unroll
    for (int i = 0; i < 4; ++i) af[i] = *(const bf16x8*)(As + aoff + i * 512);
#pragma unroll
    for (int j = 0; j < 4; ++j) bfr[j] = *(const bf16x8*)(Bs + boff + j * 512);
#pragma unroll
    for (int i = 0; i < 4; ++i)
#pragma unroll
      for (int j = 0; j < 4; ++j)
        acc[i][j] = __builtin_amdgcn_mfma_f32_16x16x32_bf16(af[i], bfr[j],
                                                            acc[i][j], 0, 0, 0);
    __syncthreads();
  }

  // C/D layout: col = lane&15, row = (lane>>4)*4 + reg
#pragma unroll
  for (int i = 0; i < 4; ++i) {
    int rbase = m0 + wr + i * 16 + qd * 4;
#pragma unroll
    for (int j = 0; j < 4; ++j) {
      int col = n0 + wc + j * 16 + la;
      float bc = bias[col];
#pragma unroll
      for (int r = 0; r < 4; ++r) {
        float v = acc[i][j][r] + bc;
        if (act) v = 0.5f * v * (1.0f + erff(v * 0.70710678118654752f));
        C[(size_t)(rbase + r) * N + col] = (bf16)v;
      }
    }
  }
}

// ---------------------------------------------------------------------------
// Embedding gather -> Xf fp32 + Xb bf16
// ---------------------------------------------------------------------------
__global__ __launch_bounds__(256) void embed_kernel(
    const int* __restrict__ idx, const float* __restrict__ emb,
    float* __restrict__ Xf, bf16* __restrict__ Xb) {
  int o = blockIdx.x * 256 + threadIdx.x;
  int t = o / Dm, d = o - t * Dm;
  float v = emb[(size_t)idx[t] * Dm + d];
  Xf[o] = v;
  Xb[o] = (bf16)v;
}

// ---------------------------------------------------------------------------
// Rotary in-place (bf16 storage, fp32 math)
// ---------------------------------------------------------------------------
__global__ __launch_bounds__(256) void rotary_kernel(bf16* __restrict__ q) {
  int o = blockIdx.x * 256 + threadIdx.x;  // < NTOK*Hn*32
  int j = o & 31;
  int h = (o >> 5) % Hn;
  int t = o / (Hn * 32);
  int l = t & (Lseq - 1);
  size_t base = (size_t)t * Dm + h * HDim;
  float inv = expf(-(float)j * (9.210340371976184f / 32.0f));
  float fr = (float)l * inv;
  float s, c;
  sincosf(fr, &s, &c);
  float x1 = (float)q[base + j], x2 = (float)q[base + j + 32];
  q[base + j] = (bf16)(x1 * c - x2 * s);
  q[base + j + 32] = (bf16)(x2 * c + x1 * s);
}

// ---------------------------------------------------------------------------
// phi = relu(q @ omega) [* mask]
// ---------------------------------------------------------------------------
__global__ __launch_bounds__(256) void phi_kernel(
    const bf16* __restrict__ qk, const float* __restrict__ omega,
    const int* __restrict__ mask, bf16* __restrict__ ph) {
  __shared__ float om[HDim * Fdim];
  int tid = threadIdx.x;
  for (int i = tid; i < HDim * Fdim; i += 256) om[i] = omega[i];
  __syncthreads();
  int o = blockIdx.x * 256 + tid;  // < NTOK*Hn*Fdim
  int f = o & 31;
  int h = (o >> 5) % Hn;
  int t = o / (Hn * Fdim);
  const bf16* qr = qk + (size_t)t * Dm + h * HDim;
  float acc = 0.0f;
#pragma unroll
  for (int d = 0; d < HDim; ++d)
    acc = fmaf((float)qr[d], om[d * Fdim + f], acc);
  acc = fmaxf(acc, 0.0f);
  if (mask) acc *= (float)mask[t];
  ph[o] = (bf16)acc;
}

// ---------------------------------------------------------------------------
// Zero KV + KSUM (ws is 0xAA-poisoned each launch). 1560*256 == 399360 elems.
// ---------------------------------------------------------------------------
__global__ __launch_bounds__(256) void zerokv_kernel(float* __restrict__ kv) {
  kv[blockIdx.x * 256 + threadIdx.x] = 0.0f;
}

// ---------------------------------------------------------------------------
// kvsum split-L: grid (Bsz*Hn, NSPLIT). Each block scans Lseq/NSPLIT tokens,
// accumulates fp32 locally, then atomicAdd into KV / KSUM.
// ---------------------------------------------------------------------------
__global__ __launch_bounds__(256) void kvsum_kernel(
    const bf16* __restrict__ phk, const bf16* __restrict__ v,
    float* __restrict__ kv, float* __restrict__ ksum) {
  __shared__ float ph_s[16][Fdim];
  __shared__ float v_s[16][HDim];
  int bh = blockIdx.x;
  int b = bh / Hn, h = bh - b * Hn;
  int tid = threadIdx.x;
  int f = tid >> 3, d0 = (tid & 7) << 3;
  const int lbeg = blockIdx.y * (Lseq / NSPLIT);
  const int lend = lbeg + (Lseq / NSPLIT);
  float acc[8] = {};
  float ks = 0.0f;
  for (int l0 = lbeg; l0 < lend; l0 += 16) {
    for (int i = tid; i < 16 * Fdim; i += 256) {
      int l = i >> 5, ff = i & 31;
      ph_s[l][ff] =
          (float)phk[((size_t)(b * Lseq + l0 + l) * Hn + h) * Fdim + ff];
    }
    for (int i = tid; i < 16 * HDim; i += 256) {
      int l = i >> 6, dd = i & 63;
      v_s[l][dd] = (float)v[((size_t)(b * Lseq + l0 + l) * Hn + h) * HDim + dd];
    }
    __syncthreads();
#pragma unroll
    for (int l = 0; l < 16; ++l) {
      float p = ph_s[l][f];
      ks += p;
#pragma unroll
      for (int q = 0; q < 8; ++q) acc[q] = fmaf(p, v_s[l][d0 + q], acc[q]);
    }
    __syncthreads();
  }
  size_t base = ((size_t)bh * Fdim + f) * HDim + d0;
#pragma unroll
  for (int q = 0; q < 8; ++q) atomicAdd(&kv[base + q], acc[q]);
  if ((tid & 7) == 0) atomicAdd(&ksum[bh * Fdim + f], ks);
}

// ---------------------------------------------------------------------------
// out[t,h,d] = (sum_f phq*kv) / (sum_f phq*ksum + 1e-6) -> bf16
// ---------------------------------------------------------------------------
__global__ __launch_bounds__(256) void attn_out_kernel(
    const bf16* __restrict__ phq, const float* __restrict__ kv,
    const float* __restrict__ ksum, bf16* __restrict__ out) {
  int o = blockIdx.x * 256 + threadIdx.x;  // < NTOK*Dm
  int d = o & 63;
  int h = (o >> 6) % Hn;
  int t = o / Dm;
  int b = t >> 11;
  const bf16* pq = phq + (size_t)t * (Hn * Fdim) + h * Fdim;
  const float* ks = ksum + ((size_t)b * Hn + h) * Fdim;
  const float* kvp = kv + ((size_t)(b * Hn + h) * Fdim) * HDim + d;
  float zden = 0.0f, acc = 0.0f;
#pragma unroll
  for (int f = 0; f < Fdim; ++f) {
    float p = (float)pq[f];
    zden = fmaf(p, ks[f], zden);
    acc = fmaf(p, kvp[(size_t)f * HDim], acc);
  }
  out[o] = (bf16)(acc / (zden + 1e-6f));
}

// ---------------------------------------------------------------------------
// Fused residual + LayerNorm: h = Xf + y (fp32), stats fp32,
// writes Xf_new (fp32, in-place safe) and Xb_new (bf16 GEMM mirror).
// ---------------------------------------------------------------------------
__global__ __launch_bounds__(256) void ln_residual_kernel(
    const bf16* __restrict__ y, const float* __restrict__ xres,
    const float* __restrict__ g, const float* __restrict__ be,
    float* __restrict__ xf_out, bf16* __restrict__ xb_out) {
  __shared__ float red[256];
  int t = blockIdx.x, tid = threadIdx.x;
  const bf16* yr = y + (size_t)t * Dm;
  const float* xr = xres + (size_t)t * Dm;
  float v0 = xr[tid] + (float)yr[tid];
  float v1 = xr[tid + 256] + (float)yr[tid + 256];
  float v2 = xr[tid + 512] + (float)yr[tid + 512];
  red[tid] = v0 + v1 + v2;
  __syncthreads();
  for (int off = 128; off > 0; off >>= 1) {
    if (tid < off) red[tid] += red[tid + off];
    __syncthreads();
  }
  float mu = red[0] * (1.0f / 768.0f);
  __syncthreads();
  float d0 = v0 - mu, d1 = v1 - mu, d2 = v2 - mu;
  red[tid] = d0 * d0 + d1 * d1 + d2 * d2;
  __syncthreads();
  for (int off = 128; off > 0; off >>= 1) {
    if (tid < off) red[tid] += red[tid + off];
    __syncthreads();
  }
  float rs = rsqrtf(red[0] * (1.0f / 768.0f) + 1e-5f);
  float o0 = d0 * rs * g[tid] + be[tid];
  float o1 = d1 * rs * g[tid + 256] + be[tid + 256];
  float o2 = d2 * rs * g[tid + 512] + be[tid + 512];
  float* xo = xf_out + (size_t)t * Dm;
  bf16* bo = xb_out + (size_t)t * Dm;
  xo[tid] = o0;
  xo[tid + 256] = o1;
  xo[tid + 512] = o2;
  bo[tid] = (bf16)o0;
  bo[tid + 256] = (bf16)o1;
  bo[tid + 512] = (bf16)o2;
}

// ---------------------------------------------------------------------------
// Final LayerNorm: fp32 in -> fp32 out (d_out).
// ---------------------------------------------------------------------------
__global__ __launch_bounds__(256) void ln_final_kernel(
    const float* __restrict__ x, const float* __restrict__ g,
    const float* __restrict__ be, float* __restrict__ out) {
  __shared__ float red[256];
  int t = blockIdx.x, tid = threadIdx.x;
  const float* xr = x + (size_t)t * Dm;
  float v0 = xr[tid], v1 = xr[tid + 256], v2 = xr[tid + 512];
  red[tid] = v0 + v1 + v2;
  __syncthreads();
  for (int off = 128; off > 0; off >>= 1) {
    if (tid < off) red[tid] += red[tid + off];
    __syncthreads();
  }
  float mu = red[0] * (1.0f / 768.0f);
  __syncthreads();
  float d0 = v0 - mu, d1 = v1 - mu, d2 = v2 - mu;
  red[tid] = d0 * d0 + d1 * d1 + d2 * d2;
  __syncthreads();
  for (int off = 128; off > 0; off >>= 1) {
    if (tid < off) red[tid] += red[tid + off];
    __syncthreads();
  }
  float rs = rsqrtf(red[0] * (1.0f / 768.0f) + 1e-5f);
  float* outr = out + (size_t)t * Dm;
  outr[tid] = d0 * rs * g[tid] + be[tid];
  outr[tid + 256] = d1 * rs * g[tid + 256] + be[tid + 256];
  outr[tid + 512] = d2 * rs * g[tid + 512] + be[tid + 512];
}

// ---------------------------------------------------------------------------
extern "C" void kernel_launch(void* const* d_in, const int* in_sizes, int n_in,
                              void* d_out, int out_size, void* d_ws,
                              size_t ws_size, hipStream_t stream) {
  const int* idx = (const int*)d_in[0];
  const int* mask = (const int*)d_in[1];
  const float* tok_emb = (const float*)d_in[2];
  const float* Wq = (const float*)d_in[3];
  const float* bq = (const float*)d_in[4];
  const float* Wk = (const float*)d_in[5];
  const float* bk = (const float*)d_in[6];
  const float* Wv = (const float*)d_in[7];
  const float* bv = (const float*)d_in[8];
  const float* Wo = (const float*)d_in[9];
  const float* bo = (const float*)d_in[10];
  const float* omega = (const float*)d_in[11];
  const float* W1 = (const float*)d_in[12];
  const float* b1 = (const float*)d_in[13];
  const float* W2 = (const float*)d_in[14];
  const float* b2 = (const float*)d_in[15];
  const float* g1 = (const float*)d_in[16];
  const float* be1 = (const float*)d_in[17];
  const float* g2 = (const float*)d_in[18];
  const float* be2 = (const float*)d_in[19];
  const float* gf = (const float*)d_in[20];
  const float* bf = (const float*)d_in[21];

  const size_t TD = (size_t)NTOK * Dm;
  const size_t WSZ = (size_t)NLayers * Dm * Dm;
  // ws layout (~181 MB; R1 proved >=203 MB usable):
  bf16* wsb = (bf16*)d_ws;
  bf16* WqT = wsb;
  bf16* WkT = WqT + WSZ;
  bf16* WvT = WkT + WSZ;
  bf16* WoT = WvT + WSZ;
  bf16* W1T = WoT + WSZ;
  bf16* W2T = W1T + WSZ;
  float* Xf = (float*)(wsb + 6 * WSZ);  // fp32 residual stream
  bf16* Ab = (bf16*)(Xf + TD);          // q/k/v temp -> attn-out -> ffn hidden
  float* KV = (float*)(Ab + TD);
  float* KSUM = KV + (size_t)Bsz * Hn * Fdim * HDim;
  // d_out aliasing: [Xb bf16 (TD)][PHQ (TD/2) | PHK (TD/2) -> y-buf (TD)]
  bf16* Xb = (bf16*)d_out;
  bf16* PHQ = Xb + TD;
  bf16* PHK = PHQ + (size_t)NTOK * Hn * Fdim;
  bf16* Yb = PHQ;  // raw GEMM output buffer (reuses PHQ+PHK region)

  dim3 wg(Dm / 32, Dm / 32, NLayers), wb(32, 8);
  wconv_kernel<<<wg, wb, 0, stream>>>(Wq, WqT);
  wconv_kernel<<<wg, wb, 0, stream>>>(Wk, WkT);
  wconv_kernel<<<wg, wb, 0, stream>>>(Wv, WvT);
  wconv_kernel<<<wg, wb, 0, stream>>>(Wo, WoT);
  wconv_kernel<<<wg, wb, 0, stream>>>(W1, W1T);
  wconv_kernel<<<wg, wb, 0, stream>>>(W2, W2T);

  dim3 gg(Dm / 128, NTOK / 128), gb(256);
  dim3 kvg(Bsz * Hn, NSPLIT);
  const int rot_grid = (NTOK * Hn * 32) / 256;
  const int phi_grid = (NTOK * Hn * Fdim) / 256;
  const int elem_grid = (NTOK * Dm) / 256;
  const int zkv_grid = (Bsz * Hn * Fdim * HDim + Bsz * Hn * Fdim) / 256;

  embed_kernel<<<elem_grid, 256, 0, stream>>>(idx, tok_emb, Xf, Xb);

  for (int i = 0; i < NLayers; ++i) {
    const size_t wo = (size_t)i * Dm * Dm;
    const size_t bo_ = (size_t)i * Dm;
    const float* omi = omega + (size_t)i * HDim * Fdim;

    // Q -> Ab -> rotary -> PHQ
    gemm_mfma_kernel<<<gg, gb, 0, stream>>>(Xb, WqT + wo, bq + bo_, Ab, 0);
    rotary_kernel<<<rot_grid, 256, 0, stream>>>(Ab);
    phi_kernel<<<phi_grid, 256, 0, stream>>>(Ab, omi, nullptr, PHQ);
    // K -> Ab -> rotary -> PHK (masked)
    gemm_mfma_kernel<<<gg, gb, 0, stream>>>(Xb, WkT + wo, bk + bo_, Ab, 0);
    rotary_kernel<<<rot_grid, 256, 0, stream>>>(Ab);
    phi_kernel<<<phi_grid, 256, 0, stream>>>(Ab, omi, mask, PHK);
    // V -> Ab; zero+accumulate kv state; attention combine -> Ab (V dead)
    gemm_mfma_kernel<<<gg, gb, 0, stream>>>(Xb, WvT + wo, bv + bo_, Ab, 0);
    zerokv_kernel<<<zkv_grid, 256, 0, stream>>>(KV);
    kvsum_kernel<<<kvg, 256, 0, stream>>>(PHK, Ab, KV, KSUM);
    attn_out_kernel<<<elem_grid, 256, 0, stream>>>(PHQ, KV, KSUM, Ab);
    // y = attn@Wo + bo -> Yb (PHQ/PHK dead); LN1(Xf + y) -> Xf, Xb
    gemm_mfma_kernel<<<gg, gb, 0, stream>>>(Ab, WoT + wo, bo + bo_, Yb, 0);
    ln_residual_kernel<<<NTOK, 256, 0, stream>>>(Yb, Xf, g1 + bo_, be1 + bo_,
                                                 Xf, Xb);
    // gelu(Xb@W1+b1) -> Ab ; y = Ab@W2+b2 -> Yb ; LN2(Xf + y) -> Xf, Xb
    gemm_mfma_kernel<<<gg, gb, 0, stream>>>(Xb, W1T + wo, b1 + bo_, Ab, 1);
    gemm_mfma_kernel<<<gg, gb, 0, stream>>>(Ab, W2T + wo, b2 + bo_, Yb, 0);
    ln_residual_kernel<<<NTOK, 256, 0, stream>>>(Yb, Xf, g2 + bo_, be2 + bo_,
                                                 Xf, Xb);
  }
  // Final LN: Xf (ws) -> d_out fp32 (Xb/Yb dead).
  ln_final_kernel<<<NTOK, 256, 0, stream>>>(Xf, gf, bf, (float*)d_out);
}

// Round 5
// 3795.362 us; speedup vs baseline: 4.5553x; 1.1841x over previous
//
// FineTuneMolFormer — Round 4: attention combine -> MFMA (kv bf16 in LDS,
// K=32 = one mfma step), zden hoisted to a tiny kernel, rotary fused into
// the QK GEMM epilogue (pair (d,d+32) = acc[i][j]/acc[i][j+2], same lane).
// ws: 6 W^T (28.3) + Xf fp32 (100.7) + Ab (50.3) + KV/KSUM/ZR (3.2) ~= 183 MB.
// d_out: [Xb bf16][PHQ|PHK / y-buf]; final LN writes d_out last.
#include <hip/hip_runtime.h>
#include <math.h>

#define Bsz 16
#define Lseq 2048
#define Dm 768
#define Hn 12
#define HDim 64
#define Fdim 32
#define NLayers 4
#define NTOK (Bsz * Lseq)
#define NSPLIT 8

typedef __bf16 bf16;
typedef bf16 bf16x8 __attribute__((ext_vector_type(8)));
typedef float f32x4 __attribute__((ext_vector_type(4)));

#define AS1(p) ((__attribute__((address_space(1))) void*)(uintptr_t)(p))
#define AS3(p) ((__attribute__((address_space(3))) void*)(p))

// ---------------------------------------------------------------------------
// Weight convert+transpose: W[l][k][n] fp32 -> Wt[l][n][k] bf16. 32x32 tiles.
// ---------------------------------------------------------------------------
__global__ __launch_bounds__(256) void wconv_kernel(const float* __restrict__ W,
                                                    bf16* __restrict__ Wt) {
  __shared__ float t[32][33];
  int l = blockIdx.z;
  int kb = blockIdx.y * 32, nb = blockIdx.x * 32;
  const float* Wl = W + (size_t)l * Dm * Dm;
  bf16* Wtl = Wt + (size_t)l * Dm * Dm;
  int tx = threadIdx.x, ty = threadIdx.y;  // 32 x 8
#pragma unroll
  for (int i = 0; i < 32; i += 8)
    t[ty + i][tx] = Wl[(size_t)(kb + ty + i) * Dm + nb + tx];
  __syncthreads();
#pragma unroll
  for (int i = 0; i < 32; i += 8)
    Wtl[(size_t)(nb + ty + i) * Dm + kb + tx] = (bf16)t[tx][ty + i];
}

// ---------------------------------------------------------------------------
// bf16 MFMA GEMM: C[M][N=768] = A[M][K=768] @ Wt[N][K]^T + bias
// (+gelu if act, +in-register rotary if rot). 128x128 tile, BK=32, 4 waves.
// ---------------------------------------------------------------------------
__global__ __launch_bounds__(256) void gemm_mfma_kernel(
    const bf16* __restrict__ A, const bf16* __restrict__ Wt,
    const float* __restrict__ bias, bf16* __restrict__ C, int act, int rot) {
  const int K = Dm, N = Dm;
  __shared__ bf16 As[128 * 32];
  __shared__ bf16 Bs[128 * 32];
  const int tid = threadIdx.x;
  const int lane = tid & 63;
  const int wave = tid >> 6;
  const int wr = (wave >> 1) << 6;
  const int wc = (wave & 1) << 6;
  const int m0 = blockIdx.y << 7;
  const int n0 = blockIdx.x << 7;
  const int c0 = tid, c1 = tid + 256;
  const bf16* a0 = A + (size_t)(m0 + (c0 >> 2)) * K + ((c0 & 3) << 3);
  const bf16* a1 = A + (size_t)(m0 + (c1 >> 2)) * K + ((c1 & 3) << 3);
  const bf16* b0 = Wt + (size_t)(n0 + (c0 >> 2)) * K + ((c0 & 3) << 3);
  const bf16* b1 = Wt + (size_t)(n0 + (c1 >> 2)) * K + ((c1 & 3) << 3);
  bf16* const As0 = As + c0 * 8;
  bf16* const As1 = As + c1 * 8;
  bf16* const Bs0 = Bs + c0 * 8;
  bf16* const Bs1 = Bs + c1 * 8;

  const int la = lane & 15, qd = lane >> 4;
  const int aoff = (wr + la) * 32 + qd * 8;
  const int boff = (wc + la) * 32 + qd * 8;

  f32x4 acc[4][4] = {};

  for (int k0 = 0; k0 < K; k0 += 32) {
    __builtin_amdgcn_global_load_lds(AS1(a0 + k0), AS3(As0), 16, 0, 0);
    __builtin_amdgcn_global_load_lds(AS1(a1 + k0), AS3(As1), 16, 0, 0);
    __builtin_amdgcn_global_load_lds(AS1(b0 + k0), AS3(Bs0), 16, 0, 0);
    __builtin_amdgcn_global_load_lds(AS1(b1 + k0), AS3(Bs1), 16, 0, 0);
    __syncthreads();
    bf16x8 af[4], bfr[4];
#pragma unroll
    for (int i = 0; i < 4; ++i) af[i] = *(const bf16x8*)(As + aoff + i * 512);
#pragma unroll
    for (int j = 0; j < 4; ++j) bfr[j] = *(const bf16x8*)(Bs + boff + j * 512);
#pragma unroll
    for (int i = 0; i < 4; ++i)
#pragma unroll
      for (int j = 0; j < 4; ++j)
        acc[i][j] = __builtin_amdgcn_mfma_f32_16x16x32_bf16(af[i], bfr[j],
                                                            acc[i][j], 0, 0, 0);
    __syncthreads();
  }

  // C/D layout: col = lane&15, row = (lane>>4)*4 + reg
  if (!rot) {
#pragma unroll
    for (int i = 0; i < 4; ++i) {
      int rbase = m0 + wr + i * 16 + qd * 4;
#pragma unroll
      for (int j = 0; j < 4; ++j) {
        int col = n0 + wc + j * 16 + la;
        float bc = bias[col];
#pragma unroll
        for (int r = 0; r < 4; ++r) {
          float v = acc[i][j][r] + bc;
          if (act) v = 0.5f * v * (1.0f + erff(v * 0.70710678118654752f));
          C[(size_t)(rbase + r) * N + col] = (bf16)v;
        }
      }
    }
  } else {
    // Wave's 64-col span == one head (n0+wc is 64-aligned). Rotary pair
    // (d, d+32) lives in acc[i][jj] / acc[i][jj+2] of the SAME lane.
#pragma unroll
    for (int i = 0; i < 4; ++i) {
      int rbase = m0 + wr + i * 16 + qd * 4;
#pragma unroll
      for (int jj = 0; jj < 2; ++jj) {
        int d = jj * 16 + la;  // 0..31 within head
        int col1 = n0 + wc + d;
        int col2 = col1 + 32;
        float b1c = bias[col1], b2c = bias[col2];
        float inv = expf(-(float)d * (9.210340371976184f / 32.0f));
#pragma unroll
        for (int r = 0; r < 4; ++r) {
          int row = rbase + r;
          int l = row & (Lseq - 1);
          float fr = (float)l * inv;
          float s, c;
          sincosf(fr, &s, &c);
          float x1 = acc[i][jj][r] + b1c;
          float x2 = acc[i][jj + 2][r] + b2c;
          C[(size_t)row * N + col1] = (bf16)(x1 * c - x2 * s);
          C[(size_t)row * N + col2] = (bf16)(x2 * c + x1 * s);
        }
      }
    }
  }
}

// ---------------------------------------------------------------------------
// Embedding gather -> Xf fp32 + Xb bf16
// ---------------------------------------------------------------------------
__global__ __launch_bounds__(256) void embed_kernel(
    const int* __restrict__ idx, const float* __restrict__ emb,
    float* __restrict__ Xf, bf16* __restrict__ Xb) {
  int o = blockIdx.x * 256 + threadIdx.x;
  int t = o / Dm, d = o - t * Dm;
  float v = emb[(size_t)idx[t] * Dm + d];
  Xf[o] = v;
  Xb[o] = (bf16)v;
}

// ---------------------------------------------------------------------------
// phi = relu(q @ omega) [* mask]
// ---------------------------------------------------------------------------
__global__ __launch_bounds__(256) void phi_kernel(
    const bf16* __restrict__ qk, const float* __restrict__ omega,
    const int* __restrict__ mask, bf16* __restrict__ ph) {
  __shared__ float om[HDim * Fdim];
  int tid = threadIdx.x;
  for (int i = tid; i < HDim * Fdim; i += 256) om[i] = omega[i];
  __syncthreads();
  int o = blockIdx.x * 256 + tid;  // < NTOK*Hn*Fdim
  int f = o & 31;
  int h = (o >> 5) % Hn;
  int t = o / (Hn * Fdim);
  const bf16* qr = qk + (size_t)t * Dm + h * HDim;
  float acc = 0.0f;
#pragma unroll
  for (int d = 0; d < HDim; ++d)
    acc = fmaf((float)qr[d], om[d * Fdim + f], acc);
  acc = fmaxf(acc, 0.0f);
  if (mask) acc *= (float)mask[t];
  ph[o] = (bf16)acc;
}

// ---------------------------------------------------------------------------
// Zero KV + KSUM (ws is 0xAA-poisoned each launch).
// ---------------------------------------------------------------------------
__global__ __launch_bounds__(256) void zerokv_kernel(float* __restrict__ kv) {
  kv[blockIdx.x * 256 + threadIdx.x] = 0.0f;
}

// ---------------------------------------------------------------------------
// kvsum split-L: grid (Bsz*Hn, NSPLIT); fp32 local accumulate + atomicAdd.
// ---------------------------------------------------------------------------
__global__ __launch_bounds__(256) void kvsum_kernel(
    const bf16* __restrict__ phk, const bf16* __restrict__ v,
    float* __restrict__ kv, float* __restrict__ ksum) {
  __shared__ float ph_s[16][Fdim];
  __shared__ float v_s[16][HDim];
  int bh = blockIdx.x;
  int b = bh / Hn, h = bh - b * Hn;
  int tid = threadIdx.x;
  int f = tid >> 3, d0 = (tid & 7) << 3;
  const int lbeg = blockIdx.y * (Lseq / NSPLIT);
  const int lend = lbeg + (Lseq / NSPLIT);
  float acc[8] = {};
  float ks = 0.0f;
  for (int l0 = lbeg; l0 < lend; l0 += 16) {
    for (int i = tid; i < 16 * Fdim; i += 256) {
      int l = i >> 5, ff = i & 31;
      ph_s[l][ff] =
          (float)phk[((size_t)(b * Lseq + l0 + l) * Hn + h) * Fdim + ff];
    }
    for (int i = tid; i < 16 * HDim; i += 256) {
      int l = i >> 6, dd = i & 63;
      v_s[l][dd] = (float)v[((size_t)(b * Lseq + l0 + l) * Hn + h) * HDim + dd];
    }
    __syncthreads();
#pragma unroll
    for (int l = 0; l < 16; ++l) {
      float p = ph_s[l][f];
      ks += p;
#pragma unroll
      for (int q = 0; q < 8; ++q) acc[q] = fmaf(p, v_s[l][d0 + q], acc[q]);
    }
    __syncthreads();
  }
  size_t base = ((size_t)bh * Fdim + f) * HDim + d0;
#pragma unroll
  for (int q = 0; q < 8; ++q) atomicAdd(&kv[base + q], acc[q]);
  if ((tid & 7) == 0) atomicAdd(&ksum[bh * Fdim + f], ks);
}

// ---------------------------------------------------------------------------
// zrecip[t,h] = 1 / (sum_f phq[t,h,f]*ksum[b,h,f] + 1e-6)
// ---------------------------------------------------------------------------
__global__ __launch_bounds__(256) void zden_kernel(
    const bf16* __restrict__ phq, const float* __restrict__ ksum,
    float* __restrict__ zr) {
  int idx = blockIdx.x * 256 + threadIdx.x;  // < NTOK*Hn
  int h = idx % Hn;
  int b = idx / (Lseq * Hn);
  const bf16* pq = phq + (size_t)idx * Fdim;
  const float* ks = ksum + ((size_t)b * Hn + h) * Fdim;
  float acc = 0.0f;
#pragma unroll
  for (int f = 0; f < Fdim; ++f) acc = fmaf((float)pq[f], ks[f], acc);
  zr[idx] = 1.0f / (acc + 1e-6f);
}

// ---------------------------------------------------------------------------
// Attention combine via MFMA: out[t,h,:] = (phq[t,h,:] @ kv[b,h]) * zr[t,h].
// Block = (256-token chunk, bh). kv -> bf16 LDS [d][f] (stride 40, 2-way ok).
// K=32 == one mfma_f32_16x16x32_bf16. Wave = 64 tokens x 64 d.
// ---------------------------------------------------------------------------
__global__ __launch_bounds__(256) void attn_mfma_kernel(
    const bf16* __restrict__ phq, const float* __restrict__ kv,
    const float* __restrict__ zr, bf16* __restrict__ out) {
  __shared__ bf16 kvb[64 * 40];
  int bh = blockIdx.y;
  int b = bh / Hn, h = bh - b * Hn;
  int tid = threadIdx.x, lane = tid & 63, wave = tid >> 6;
  {  // transpose-load kv[f][d] fp32 -> kvb[d][f] bf16
    int d = tid >> 2, f0 = (tid & 3) << 3;
    const float* src = kv + ((size_t)bh * Fdim + f0) * HDim + d;
    bf16x8 tmp;
#pragma unroll
    for (int q = 0; q < 8; ++q) tmp[q] = (bf16)src[(size_t)q * HDim];
    *(bf16x8*)(kvb + d * 40 + f0) = tmp;
  }
  __syncthreads();
  const int la = lane & 15, qd = lane >> 4;
  const int t0 = b * Lseq + blockIdx.x * 256 + wave * 64;
  bf16x8 bfr[4];
#pragma unroll
  for (int jt = 0; jt < 4; ++jt)
    bfr[jt] = *(const bf16x8*)(kvb + (jt * 16 + la) * 40 + qd * 8);
  bf16x8 af[4];
#pragma unroll
  for (int i = 0; i < 4; ++i)
    af[i] = *(const bf16x8*)(phq +
                             ((size_t)(t0 + i * 16 + la) * Hn + h) * Fdim +
                             qd * 8);
  f32x4 acc[4][4] = {};
#pragma unroll
  for (int i = 0; i < 4; ++i)
#pragma unroll
    for (int jt = 0; jt < 4; ++jt)
      acc[i][jt] = __builtin_amdgcn_mfma_f32_16x16x32_bf16(af[i], bfr[jt],
                                                           acc[i][jt], 0, 0, 0);
#pragma unroll
  for (int i = 0; i < 4; ++i) {
    int rbase = t0 + i * 16 + qd * 4;
#pragma unroll
    for (int r = 0; r < 4; ++r) {
      float z = zr[(size_t)(rbase + r) * Hn + h];
#pragma unroll
      for (int jt = 0; jt < 4; ++jt)
        out[(size_t)(rbase + r) * Dm + h * HDim + jt * 16 + la] =
            (bf16)(acc[i][jt][r] * z);
    }
  }
}

// ---------------------------------------------------------------------------
// Fused residual + LayerNorm: h = Xf + y; writes Xf (fp32) and Xb (bf16).
// ---------------------------------------------------------------------------
__global__ __launch_bounds__(256) void ln_residual_kernel(
    const bf16* __restrict__ y, const float* __restrict__ xres,
    const float* __restrict__ g, const float* __restrict__ be,
    float* __restrict__ xf_out, bf16* __restrict__ xb_out) {
  __shared__ float red[256];
  int t = blockIdx.x, tid = threadIdx.x;
  const bf16* yr = y + (size_t)t * Dm;
  const float* xr = xres + (size_t)t * Dm;
  float v0 = xr[tid] + (float)yr[tid];
  float v1 = xr[tid + 256] + (float)yr[tid + 256];
  float v2 = xr[tid + 512] + (float)yr[tid + 512];
  red[tid] = v0 + v1 + v2;
  __syncthreads();
  for (int off = 128; off > 0; off >>= 1) {
    if (tid < off) red[tid] += red[tid + off];
    __syncthreads();
  }
  float mu = red[0] * (1.0f / 768.0f);
  __syncthreads();
  float d0 = v0 - mu, d1 = v1 - mu, d2 = v2 - mu;
  red[tid] = d0 * d0 + d1 * d1 + d2 * d2;
  __syncthreads();
  for (int off = 128; off > 0; off >>= 1) {
    if (tid < off) red[tid] += red[tid + off];
    __syncthreads();
  }
  float rs = rsqrtf(red[0] * (1.0f / 768.0f) + 1e-5f);
  float o0 = d0 * rs * g[tid] + be[tid];
  float o1 = d1 * rs * g[tid + 256] + be[tid + 256];
  float o2 = d2 * rs * g[tid + 512] + be[tid + 512];
  float* xo = xf_out + (size_t)t * Dm;
  bf16* bo = xb_out + (size_t)t * Dm;
  xo[tid] = o0;
  xo[tid + 256] = o1;
  xo[tid + 512] = o2;
  bo[tid] = (bf16)o0;
  bo[tid + 256] = (bf16)o1;
  bo[tid + 512] = (bf16)o2;
}

// ---------------------------------------------------------------------------
// Final LayerNorm: fp32 in -> fp32 out (d_out).
// ---------------------------------------------------------------------------
__global__ __launch_bounds__(256) void ln_final_kernel(
    const float* __restrict__ x, const float* __restrict__ g,
    const float* __restrict__ be, float* __restrict__ out) {
  __shared__ float red[256];
  int t = blockIdx.x, tid = threadIdx.x;
  const float* xr = x + (size_t)t * Dm;
  float v0 = xr[tid], v1 = xr[tid + 256], v2 = xr[tid + 512];
  red[tid] = v0 + v1 + v2;
  __syncthreads();
  for (int off = 128; off > 0; off >>= 1) {
    if (tid < off) red[tid] += red[tid + off];
    __syncthreads();
  }
  float mu = red[0] * (1.0f / 768.0f);
  __syncthreads();
  float d0 = v0 - mu, d1 = v1 - mu, d2 = v2 - mu;
  red[tid] = d0 * d0 + d1 * d1 + d2 * d2;
  __syncthreads();
  for (int off = 128; off > 0; off >>= 1) {
    if (tid < off) red[tid] += red[tid + off];
    __syncthreads();
  }
  float rs = rsqrtf(red[0] * (1.0f / 768.0f) + 1e-5f);
  float* outr = out + (size_t)t * Dm;
  outr[tid] = d0 * rs * g[tid] + be[tid];
  outr[tid + 256] = d1 * rs * g[tid + 256] + be[tid + 256];
  outr[tid + 512] = d2 * rs * g[tid + 512] + be[tid + 512];
}

// ---------------------------------------------------------------------------
extern "C" void kernel_launch(void* const* d_in, const int* in_sizes, int n_in,
                              void* d_out, int out_size, void* d_ws,
                              size_t ws_size, hipStream_t stream) {
  const int* idx = (const int*)d_in[0];
  const int* mask = (const int*)d_in[1];
  const float* tok_emb = (const float*)d_in[2];
  const float* Wq = (const float*)d_in[3];
  const float* bq = (const float*)d_in[4];
  const float* Wk = (const float*)d_in[5];
  const float* bk = (const float*)d_in[6];
  const float* Wv = (const float*)d_in[7];
  const float* bv = (const float*)d_in[8];
  const float* Wo = (const float*)d_in[9];
  const float* bo = (const float*)d_in[10];
  const float* omega = (const float*)d_in[11];
  const float* W1 = (const float*)d_in[12];
  const float* b1 = (const float*)d_in[13];
  const float* W2 = (const float*)d_in[14];
  const float* b2 = (const float*)d_in[15];
  const float* g1 = (const float*)d_in[16];
  const float* be1 = (const float*)d_in[17];
  const float* g2 = (const float*)d_in[18];
  const float* be2 = (const float*)d_in[19];
  const float* gf = (const float*)d_in[20];
  const float* bf = (const float*)d_in[21];

  const size_t TD = (size_t)NTOK * Dm;
  const size_t WSZ = (size_t)NLayers * Dm * Dm;
  bf16* wsb = (bf16*)d_ws;
  bf16* WqT = wsb;
  bf16* WkT = WqT + WSZ;
  bf16* WvT = WkT + WSZ;
  bf16* WoT = WvT + WSZ;
  bf16* W1T = WoT + WSZ;
  bf16* W2T = W1T + WSZ;
  float* Xf = (float*)(wsb + 6 * WSZ);  // fp32 residual stream
  bf16* Ab = (bf16*)(Xf + TD);          // q/k/v -> attn-out -> ffn hidden
  float* KV = (float*)(Ab + TD);
  float* KSUM = KV + (size_t)Bsz * Hn * Fdim * HDim;
  float* ZR = KSUM + (size_t)Bsz * Hn * Fdim;  // zrecip[t,h], 1.5 MB
  // d_out aliasing: [Xb bf16 (TD)][PHQ (TD/2) | PHK (TD/2) -> y-buf (TD)]
  bf16* Xb = (bf16*)d_out;
  bf16* PHQ = Xb + TD;
  bf16* PHK = PHQ + (size_t)NTOK * Hn * Fdim;
  bf16* Yb = PHQ;

  dim3 wg(Dm / 32, Dm / 32, NLayers), wb(32, 8);
  wconv_kernel<<<wg, wb, 0, stream>>>(Wq, WqT);
  wconv_kernel<<<wg, wb, 0, stream>>>(Wk, WkT);
  wconv_kernel<<<wg, wb, 0, stream>>>(Wv, WvT);
  wconv_kernel<<<wg, wb, 0, stream>>>(Wo, WoT);
  wconv_kernel<<<wg, wb, 0, stream>>>(W1, W1T);
  wconv_kernel<<<wg, wb, 0, stream>>>(W2, W2T);

  dim3 gg(Dm / 128, NTOK / 128), gb(256);
  dim3 kvg(Bsz * Hn, NSPLIT);
  dim3 ag(Lseq / 256, Bsz * Hn);
  const int phi_grid = (NTOK * Hn * Fdim) / 256;
  const int elem_grid = (NTOK * Dm) / 256;
  const int zden_grid = (NTOK * Hn) / 256;
  const int zkv_grid = (Bsz * Hn * Fdim * HDim + Bsz * Hn * Fdim) / 256;

  embed_kernel<<<elem_grid, 256, 0, stream>>>(idx, tok_emb, Xf, Xb);

  for (int i = 0; i < NLayers; ++i) {
    const size_t wo = (size_t)i * Dm * Dm;
    const size_t bo_ = (size_t)i * Dm;
    const float* omi = omega + (size_t)i * HDim * Fdim;

    // Q (rotary fused) -> Ab -> PHQ
    gemm_mfma_kernel<<<gg, gb, 0, stream>>>(Xb, WqT + wo, bq + bo_, Ab, 0, 1);
    phi_kernel<<<phi_grid, 256, 0, stream>>>(Ab, omi, nullptr, PHQ);
    // K (rotary fused) -> Ab -> PHK (masked)
    gemm_mfma_kernel<<<gg, gb, 0, stream>>>(Xb, WkT + wo, bk + bo_, Ab, 0, 1);
    phi_kernel<<<phi_grid, 256, 0, stream>>>(Ab, omi, mask, PHK);
    // V -> Ab; kv state; zden; MFMA attention combine -> Ab
    gemm_mfma_kernel<<<gg, gb, 0, stream>>>(Xb, WvT + wo, bv + bo_, Ab, 0, 0);
    zerokv_kernel<<<zkv_grid, 256, 0, stream>>>(KV);
    kvsum_kernel<<<kvg, 256, 0, stream>>>(PHK, Ab, KV, KSUM);
    zden_kernel<<<zden_grid, 256, 0, stream>>>(PHQ, KSUM, ZR);
    attn_mfma_kernel<<<ag, 256, 0, stream>>>(PHQ, KV, ZR, Ab);
    // y = attn@Wo + bo -> Yb; LN1(Xf + y) -> Xf, Xb
    gemm_mfma_kernel<<<gg, gb, 0, stream>>>(Ab, WoT + wo, bo + bo_, Yb, 0, 0);
    ln_residual_kernel<<<NTOK, 256, 0, stream>>>(Yb, Xf, g1 + bo_, be1 + bo_,
                                                 Xf, Xb);
    // gelu(Xb@W1+b1) -> Ab; y = Ab@W2+b2 -> Yb; LN2(Xf + y) -> Xf, Xb
    gemm_mfma_kernel<<<gg, gb, 0, stream>>>(Xb, W1T + wo, b1 + bo_, Ab, 1, 0);
    gemm_mfma_kernel<<<gg, gb, 0, stream>>>(Ab, W2T + wo, b2 + bo_, Yb, 0, 0);
    ln_residual_kernel<<<NTOK, 256, 0, stream>>>(Yb, Xf, g2 + bo_, be2 + bo_,
                                                 Xf, Xb);
  }
  ln_final_kernel<<<NTOK, 256, 0, stream>>>(Xf, gf, bf, (float*)d_out);
}